// Round 8
// baseline (1466.937 us; speedup 1.0000x reference)
//
#include <hip/hip_runtime.h>
#include <hip/hip_bf16.h>

typedef __attribute__((ext_vector_type(8))) __bf16 bf16x8;
typedef __attribute__((ext_vector_type(4))) float f32x4;
typedef __attribute__((ext_vector_type(8))) unsigned short ushort8;
typedef unsigned short ushort;

__device__ __forceinline__ ushort f2bf(float f) {
    unsigned u = __builtin_bit_cast(unsigned, f);
    unsigned r = (u + 0x7fffu + ((u >> 16) & 1u)) >> 16;
    return (ushort)r;
}

__device__ __forceinline__ unsigned cvtpk(float a, float b) {
    unsigned r;
    asm("v_cvt_pk_bf16_f32 %0, %1, %2" : "=v"(r) : "v"(a), "v"(b));
    return r;
}

// ---------------------------------------------------------------------------
// Pack layer-1 weights (4x [512,256] fp32) and layer-2 weights into bf16
// MFMA-B-fragment order in ws. (unchanged)
// W1p ushort offset = ((n16*16 + ksg)*64 + l)*8 ; n16 = j*16 + colfrag
// ---------------------------------------------------------------------------
__global__ __launch_bounds__(256) void k_pack(
    const float* __restrict__ w1a, const float* __restrict__ w1b,
    const float* __restrict__ w1c, const float* __restrict__ w1d,
    const float* __restrict__ w2a, const float* __restrict__ w2b,
    const float* __restrict__ w2c, const float* __restrict__ w2d,
    ushort* __restrict__ W1p, ushort* __restrict__ W2p)
{
    int c = blockIdx.x * 256 + threadIdx.x;
    if (c < 65536) {
        int l = c & 63, ks = (c >> 6) & 15, n16 = c >> 10;
        int j = n16 >> 4;
        int col = (n16 & 15) * 16 + (l & 15);
        int kb = ks * 32 + (l >> 4) * 8;
        const float* W = (j == 0) ? w1a : (j == 1) ? w1b : (j == 2) ? w1c : w1d;
        ushort8 o;
#pragma unroll
        for (int e = 0; e < 8; ++e) o[e] = f2bf(W[(size_t)(kb + e) * 256 + col]);
        *reinterpret_cast<ushort8*>(W1p + (size_t)c * 8) = o;
    } else if (c < 65536 + 10752) {
        int cc = c - 65536;
        int l = cc & 63, ks = (cc >> 6) & 7, f = cc >> 9;
        int colg = f * 16 + (l & 15);
        int kb = ks * 32 + (l >> 4) * 8;
        const float* W = nullptr; int lc = 0, ncols = 1;
        if (colg < 192)        { W = w2a; lc = colg;       ncols = 192; }
        else if (colg < 256)   { W = w2b; lc = colg - 192; ncols = 64; }
        else if (colg < 320)   { W = w2c; lc = colg - 256; ncols = 64; }
        else if (colg == 320)  { W = w2d; lc = 0;          ncols = 1; }
        ushort8 o;
#pragma unroll
        for (int e = 0; e < 8; ++e)
            o[e] = W ? f2bf(W[(size_t)(kb + e) * ncols + lc]) : (ushort)0;
        *reinterpret_cast<ushort8*>(W2p + (size_t)cc * 8) = o;
    }
}

// ---------------------------------------------------------------------------
// Layer-1 GEMM v6: block = 256 rows x 1024 cols, 1024 thr = 16 waves
// (4 row-groups x 4 col-groups). K in 2 chunks of 256 staged into 128 KB
// swizzled LDS; acc (wave's 64x256 = 256 AGPR) persists across chunks.
// Per it: A loaded once, reused across 4 sub-col-groups; B via dist-2 ring.
// Unique B traffic per grid: 256 blocks x 1 MB = 256 MB (was 1 GB), and
// row-group waves hit the same B lines in L2. Epilogue reuses LDS (aliased).
// LDS 136 KB -> 1 block/CU, 16 waves = 4/SIMD.
// ---------------------------------------------------------------------------
__global__ __launch_bounds__(1024, 1) void k_l1(
    const float* __restrict__ S, const ushort* __restrict__ W1p,
    const float* __restrict__ b0, const float* __restrict__ b1,
    const float* __restrict__ b2, const float* __restrict__ b3,
    ushort* __restrict__ hid, int m0)
{
    __shared__ ushort smem[16 * 64 * 68];  // 139264 B; aliased: sA (128 KB) / sE
    char* sAb = reinterpret_cast<char*>(smem);

    int tid = threadIdx.x, l = tid & 63, wave = tid >> 6;  // wave 0..15
    int rg = wave >> 2, wc = wave & 3;
    int lr = l & 15, lg = l >> 4;
    int mt = blockIdx.x;

    // per-lane packed-B lane base
    const ushort* Wl = W1p + (size_t)l * 8;

    f32x4 acc[4][4][4] = {};  // [scg][mf][nf], 256 regs
    bf16x8 ring[3][8];

    // B-issue for step st: chunk=st>>4, it_l=(st>>2)&3, scg=st&3
#define ISSUE_B(st, buf)                                                       \
    {                                                                          \
        const int _c = (st) >> 4, _it = ((st) >> 2) & 3, _sg = (st) & 3;       \
        _Pragma("unroll")                                                      \
        for (int ks = 0; ks < 2; ++ks)                                         \
            _Pragma("unroll")                                                  \
            for (int nf = 0; nf < 4; ++nf)                                     \
                ring[buf][ks * 4 + nf] = *reinterpret_cast<const bf16x8*>(     \
                    Wl + (size_t)((wc * 16 + _sg * 4 + nf) * 16 +              \
                                  _c * 8 + _it * 2 + ks) * 512);               \
    }

    // prologue: steps 0,1 fly during chunk-0 staging
    ISSUE_B(0, 0)
    ISSUE_B(1, 1)

    // ---- stage chunk 0: S[256 rows][k 0..256) fp32 -> bf16 swizzled
    {
        const float* Sc = S + (size_t)(m0 + mt * 256) * 512;
#pragma unroll
        for (int i = 0; i < 8; ++i) {
            int g = i * 1024 + tid;
            int row = g >> 5, kc = g & 31;
            const float4* gp = reinterpret_cast<const float4*>(Sc + (size_t)row * 512 + kc * 8);
            float4 fa = gp[0], fb = gp[1];
            uint4 o;
            o.x = cvtpk(fa.x, fa.y); o.y = cvtpk(fa.z, fa.w);
            o.z = cvtpk(fb.x, fb.y); o.w = cvtpk(fb.z, fb.w);
            *reinterpret_cast<uint4*>(sAb + (size_t)(row * 32 + (kc ^ (row & 7))) * 16) = o;
        }
    }
    __syncthreads();

#pragma unroll
    for (int chunk = 0; chunk < 2; ++chunk) {
        if (chunk == 1) {
            __syncthreads();  // all waves done reading chunk-0 sA
            const float* Sc = S + (size_t)(m0 + mt * 256) * 512 + 256;
#pragma unroll
            for (int i = 0; i < 8; ++i) {
                int g = i * 1024 + tid;
                int row = g >> 5, kc = g & 31;
                const float4* gp = reinterpret_cast<const float4*>(Sc + (size_t)row * 512 + kc * 8);
                float4 fa = gp[0], fb = gp[1];
                uint4 o;
                o.x = cvtpk(fa.x, fa.y); o.y = cvtpk(fa.z, fa.w);
                o.z = cvtpk(fb.x, fb.y); o.w = cvtpk(fb.z, fb.w);
                *reinterpret_cast<uint4*>(sAb + (size_t)(row * 32 + (kc ^ (row & 7))) * 16) = o;
            }
            __syncthreads();
        }
#pragma unroll
        for (int it_l = 0; it_l < 4; ++it_l) {
            // A fragments for this it (K=64), shared across the 4 sub-col-groups
            bf16x8 a[2][4];
#pragma unroll
            for (int ks = 0; ks < 2; ++ks)
#pragma unroll
                for (int mf = 0; mf < 4; ++mf) {
                    int row = rg * 64 + mf * 16 + lr;
                    int kc = it_l * 8 + ks * 4 + lg;
                    a[ks][mf] = *reinterpret_cast<const bf16x8*>(
                        sAb + (size_t)(row * 32 + (kc ^ (row & 7))) * 16);
                }
#pragma unroll
            for (int scg = 0; scg < 4; ++scg) {
                const int st = chunk * 16 + it_l * 4 + scg;
                if (st + 2 < 32) {
                    const int s2 = st + 2;
                    ISSUE_B(s2, s2 % 3)
                }
#pragma unroll
                for (int ks = 0; ks < 2; ++ks)
#pragma unroll
                    for (int nf = 0; nf < 4; ++nf)
#pragma unroll
                        for (int mf = 0; mf < 4; ++mf)
                            acc[scg][mf][nf] = __builtin_amdgcn_mfma_f32_16x16x32_bf16(
                                a[ks][mf], ring[st % 3][ks * 4 + nf], acc[scg][mf][nf], 0, 0, 0);
            }
        }
    }
#undef ISSUE_B

    __syncthreads();  // sA no longer needed; reuse as epilogue scratch

    const float* bp = (wc == 0) ? b0 : (wc == 1) ? b1 : (wc == 2) ? b2 : b3;
    ushort* myT = smem + (size_t)wave * (64 * 68);  // per-wave 64x64 slice, stride 68

#pragma unroll
    for (int scg = 0; scg < 4; ++scg) {
        // bias + relu -> bf16 into per-wave transpose slice
#pragma unroll
        for (int nf = 0; nf < 4; ++nf) {
            float bv = bp[scg * 64 + nf * 16 + lr];
#pragma unroll
            for (int mf = 0; mf < 4; ++mf)
#pragma unroll
                for (int r = 0; r < 4; ++r) {
                    float v = acc[scg][mf][nf][r] + bv;
                    v = v > 0.f ? v : 0.f;
                    myT[(mf * 16 + lg * 4 + r) * 68 + nf * 16 + lr] = f2bf(v);
                }
        }
        // coalesced write: 8 lanes per row, 16 B each -> 128 B contiguous
        int row8 = l >> 3, seg = l & 7;
#pragma unroll
        for (int rr = 0; rr < 8; ++rr) {
            int row = rr * 8 + row8;
            ushort8 o = *reinterpret_cast<const ushort8*>(myT + row * 68 + seg * 8);
            *reinterpret_cast<ushort8*>(
                hid + (size_t)(mt * 256 + rg * 64 + row) * 1024 +
                wc * 256 + scg * 64 + seg * 8) = o;
        }
    }
}

// ---------------------------------------------------------------------------
// Layer-2 (4 block GEMMs via MFMA) + mixer, fused. 32 samples / wg. (unchanged)
// ---------------------------------------------------------------------------
__global__ __launch_bounds__(256) void k_l2mix(
    const ushort* __restrict__ hid, const ushort* __restrict__ W2p,
    const float* __restrict__ bw1, const float* __restrict__ bb1,
    const float* __restrict__ bw2, const float* __restrict__ bb2,
    const float* __restrict__ q, float* __restrict__ out, int m0)
{
    __shared__ float sO[32 * 336];  // 43 KB
    int tid = threadIdx.x, l = tid & 63, w = tid >> 6;
    int lr = l & 15, lg = l >> 4;
    int sb = blockIdx.x * 32;

    const int fs[5] = {0, 6, 12, 17, 21};
    int jloaded = -1;
    bf16x8 a[2][8];
    for (int f = fs[w]; f < fs[w + 1]; ++f) {
        int j = (f < 12) ? 0 : (f < 16) ? 1 : (f < 20) ? 2 : 3;
        if (j != jloaded) {
#pragma unroll
            for (int mf = 0; mf < 2; ++mf)
#pragma unroll
                for (int ks = 0; ks < 8; ++ks)
                    a[mf][ks] = *reinterpret_cast<const bf16x8*>(
                        hid + (size_t)(sb + mf * 16 + lr) * 1024 + j * 256 + ks * 32 + lg * 8);
            jloaded = j;
        }
        f32x4 acc[2] = {};
#pragma unroll
        for (int ks = 0; ks < 8; ++ks) {
            bf16x8 b = *reinterpret_cast<const bf16x8*>(W2p + ((size_t)(f * 8 + ks) * 64 + l) * 8);
            acc[0] = __builtin_amdgcn_mfma_f32_16x16x32_bf16(a[0][ks], b, acc[0], 0, 0, 0);
            acc[1] = __builtin_amdgcn_mfma_f32_16x16x32_bf16(a[1][ks], b, acc[1], 0, 0, 0);
        }
        int colg = f * 16 + lr;
        float bv = 0.f; bool doabs = false;
        if (colg < 192)       { bv = bw1[colg];       doabs = true; }
        else if (colg < 256)  { bv = bb1[colg - 192]; doabs = false; }
        else if (colg < 320)  { bv = bw2[colg - 256]; doabs = true; }
        else if (colg == 320) { bv = bb2[0];          doabs = false; }
#pragma unroll
        for (int mf = 0; mf < 2; ++mf)
#pragma unroll
            for (int r = 0; r < 4; ++r) {
                float v = acc[mf][r] + bv;
                if (doabs) v = fabsf(v);
                sO[(mf * 16 + lg * 4 + r) * 336 + colg] = v;
            }
    }
    __syncthreads();

    // mixer: 8 threads per sample, each covers 8 of the 64 hidden units
    int sm = tid >> 3, oct = tid & 7;
    const float* qs = q + (size_t)(m0 + sb + sm) * 3;
    float q0 = qs[0], q1 = qs[1], q2 = qs[2];
    const float* ob = sO + sm * 336;
    float res[3];
#pragma unroll
    for (int n = 0; n < 3; ++n) {
        float qa, qb, qc;
        if (n == 0)      { qa = q0; qb = q1; qc = q2; }
        else if (n == 1) { qa = q1; qb = q0; qc = q2; }
        else             { qa = q2; qb = q0; qc = q1; }
        float accm = 0.f;
#pragma unroll
        for (int hh = 0; hh < 8; ++hh) {
            int hc = oct * 8 + hh;
            float hv = ob[192 + hc] + qa * ob[hc] + qb * ob[64 + hc] + qc * ob[128 + hc];
            float ev = hv > 0.f ? hv : expm1f(hv);
            accm += ev * ob[256 + hc];
        }
        accm += __shfl_xor(accm, 1);
        accm += __shfl_xor(accm, 2);
        accm += __shfl_xor(accm, 4);
        res[n] = accm;
    }
    if (oct == 0) {
        float b2v = ob[320];
        float* op = out + (size_t)(m0 + sb + sm) * 3;
        op[0] = res[0] + b2v;
        op[1] = res[1] + b2v;
        op[2] = res[2] + b2v;
    }
}

extern "C" void kernel_launch(void* const* d_in, const int* in_sizes, int n_in,
                              void* d_out, int out_size, void* d_ws, size_t ws_size,
                              hipStream_t stream)
{
    const float* q      = (const float*)d_in[0];
    const float* S      = (const float*)d_in[1];
    const float* hw1_W1 = (const float*)d_in[2];
    const float* hw1_b1 = (const float*)d_in[3];
    const float* hw1_W2 = (const float*)d_in[4];
    const float* hw1_b2 = (const float*)d_in[5];
    const float* hb1_W1 = (const float*)d_in[6];
    const float* hb1_b1 = (const float*)d_in[7];
    const float* hb1_W2 = (const float*)d_in[8];
    const float* hb1_b2 = (const float*)d_in[9];
    const float* hw2_W1 = (const float*)d_in[10];
    const float* hw2_b1 = (const float*)d_in[11];
    const float* hw2_W2 = (const float*)d_in[12];
    const float* hw2_b2 = (const float*)d_in[13];
    const float* hb2_W1 = (const float*)d_in[14];
    const float* hb2_b1 = (const float*)d_in[15];
    const float* hb2_W2 = (const float*)d_in[16];
    const float* hb2_b2 = (const float*)d_in[17];

    int TB = in_sizes[1] / 512;

    ushort* W1p = (ushort*)d_ws;            // 1 MB (65536 chunks * 16 B)
    ushort* W2p = W1p + (size_t)65536 * 8;  // 168 KB
    ushort* hid = W2p + (size_t)10752 * 8;
    size_t used = (size_t)(65536 + 10752) * 16;
    size_t hid_cap = (ws_size > used) ? (ws_size - used) : 0;
    long long max_chunk = (long long)(hid_cap / 2048);  // samples (1024 bf16 each)
    max_chunk &= ~255LL;
    if (max_chunk > TB) max_chunk = TB;
    if (max_chunk < 256) max_chunk = 256;  // best effort

    k_pack<<<dim3(298), dim3(256), 0, stream>>>(
        hw1_W1, hb1_W1, hw2_W1, hb2_W1,
        hw1_W2, hb1_W2, hw2_W2, hb2_W2, W1p, W2p);

    for (int m0 = 0; m0 < TB; m0 += (int)max_chunk) {
        int mc = TB - m0;
        if (mc > max_chunk) mc = (int)max_chunk;
        k_l1<<<dim3(mc / 256), dim3(1024), 0, stream>>>(
            S, W1p, hw1_b1, hb1_b1, hw2_b1, hb2_b1, hid, m0);
        k_l2mix<<<dim3(mc / 32), dim3(256), 0, stream>>>(
            hid, W2p, hw1_b2, hb1_b2, hw2_b2, hb2_b2, q, (float*)d_out, m0);
    }
}

// Round 9
// 234.728 us; speedup vs baseline: 6.2495x; 6.2495x over previous
//
#include <hip/hip_runtime.h>
#include <hip/hip_bf16.h>

typedef __attribute__((ext_vector_type(8))) __bf16 bf16x8;
typedef __attribute__((ext_vector_type(4))) float f32x4;
typedef __attribute__((ext_vector_type(8))) unsigned short ushort8;
typedef unsigned short ushort;

__device__ __forceinline__ ushort f2bf(float f) {
    unsigned u = __builtin_bit_cast(unsigned, f);
    unsigned r = (u + 0x7fffu + ((u >> 16) & 1u)) >> 16;
    return (ushort)r;
}

__device__ __forceinline__ unsigned cvtpk(float a, float b) {
    unsigned r;
    asm("v_cvt_pk_bf16_f32 %0, %1, %2" : "=v"(r) : "v"(a), "v"(b));
    return r;
}

// ---------------------------------------------------------------------------
// Pack layer-1 weights (4x [512,256] fp32) and layer-2 weights into bf16
// MFMA-B-fragment order in ws. (unchanged)
// W1p ushort offset = ((n16*16 + ksg)*64 + l)*8 ; n16 = j*16 + colfrag
// ---------------------------------------------------------------------------
__global__ __launch_bounds__(256) void k_pack(
    const float* __restrict__ w1a, const float* __restrict__ w1b,
    const float* __restrict__ w1c, const float* __restrict__ w1d,
    const float* __restrict__ w2a, const float* __restrict__ w2b,
    const float* __restrict__ w2c, const float* __restrict__ w2d,
    ushort* __restrict__ W1p, ushort* __restrict__ W2p)
{
    int c = blockIdx.x * 256 + threadIdx.x;
    if (c < 65536) {
        int l = c & 63, ks = (c >> 6) & 15, n16 = c >> 10;
        int j = n16 >> 4;
        int col = (n16 & 15) * 16 + (l & 15);
        int kb = ks * 32 + (l >> 4) * 8;
        const float* W = (j == 0) ? w1a : (j == 1) ? w1b : (j == 2) ? w1c : w1d;
        ushort8 o;
#pragma unroll
        for (int e = 0; e < 8; ++e) o[e] = f2bf(W[(size_t)(kb + e) * 256 + col]);
        *reinterpret_cast<ushort8*>(W1p + (size_t)c * 8) = o;
    } else if (c < 65536 + 10752) {
        int cc = c - 65536;
        int l = cc & 63, ks = (cc >> 6) & 7, f = cc >> 9;
        int colg = f * 16 + (l & 15);
        int kb = ks * 32 + (l >> 4) * 8;
        const float* W = nullptr; int lc = 0, ncols = 1;
        if (colg < 192)        { W = w2a; lc = colg;       ncols = 192; }
        else if (colg < 256)   { W = w2b; lc = colg - 192; ncols = 64; }
        else if (colg < 320)   { W = w2c; lc = colg - 256; ncols = 64; }
        else if (colg == 320)  { W = w2d; lc = 0;          ncols = 1; }
        ushort8 o;
#pragma unroll
        for (int e = 0; e < 8; ++e)
            o[e] = W ? f2bf(W[(size_t)(kb + e) * ncols + lc]) : (ushort)0;
        *reinterpret_cast<ushort8*>(W2p + (size_t)cc * 8) = o;
    }
}

// ---------------------------------------------------------------------------
// Layer-1 GEMM v7: block = 128 rows x 256 cols (one hypernet j = blockIdx.y),
// 256 thr = 4 waves; wave w owns cols [w*64,(w+1)*64), ALL 128 rows:
// acc[8][4] = 128 regs. B-bytes/MFMA-cyc halves vs v2-v5 (26 vs 52) =>
// L2-BW ceiling rises 27% -> 53%. K staged in 2 chunks of 256 into 64 KB LDS
// with slot swizzle (kc + 4*(row&7))&31 -> exactly 2-way (free) on both
// ds_write_b128 staging and ds_read_b128 A-frags. Epilogue aliases dead sA.
// LDS 64 KB -> 2 blocks/CU. Grid (rowT, j): consecutive blocks share the
// 256 KB B panel per XCD (L2-hot).
// ---------------------------------------------------------------------------
__global__ __launch_bounds__(256, 2) void k_l1(
    const float* __restrict__ S, const ushort* __restrict__ W1p,
    const float* __restrict__ b0, const float* __restrict__ b1,
    const float* __restrict__ b2, const float* __restrict__ b3,
    ushort* __restrict__ hid, int m0)
{
    __shared__ ushort smem[128 * 256];  // 64 KB
    char* sAb = reinterpret_cast<char*>(smem);

    int tid = threadIdx.x, l = tid & 63, w = tid >> 6;  // w in 0..3
    int lr = l & 15, lg = l >> 4;
    int mt = blockIdx.x, ct = blockIdx.y;
    const float* Srow = S + (size_t)(m0 + mt * 128) * 512;

    f32x4 acc[8][4] = {};

#pragma unroll
    for (int chunk = 0; chunk < 2; ++chunk) {
        if (chunk) __syncthreads();  // all waves done reading prev chunk
        // ---- stage S[128 rows][k chunk*256 .. +256) fp32 -> bf16, swizzled
#pragma unroll
        for (int i = 0; i < 16; ++i) {
            int c = i * 256 + tid;
            int row = c >> 5, kc = c & 31;
            const float4* g = reinterpret_cast<const float4*>(
                Srow + (size_t)row * 512 + chunk * 256 + kc * 8);
            float4 fa = g[0], fb = g[1];
            uint4 o;
            o.x = cvtpk(fa.x, fa.y); o.y = cvtpk(fa.z, fa.w);
            o.z = cvtpk(fb.x, fb.y); o.w = cvtpk(fb.z, fb.w);
            int slot = (kc + ((row & 7) << 2)) & 31;
            *reinterpret_cast<uint4*>(sAb + (size_t)(row * 32 + slot) * 16) = o;
        }
        __syncthreads();

#pragma unroll
        for (int it = 0; it < 4; ++it) {
#pragma unroll
            for (int ks = 0; ks < 2; ++ks) {
                // B first (L2 loads, hoistable by compiler), then A, then MFMA
                bf16x8 b[4];
#pragma unroll
                for (int nf = 0; nf < 4; ++nf) {
                    int n16 = ct * 16 + w * 4 + nf;
                    int ksg = chunk * 8 + it * 2 + ks;
                    b[nf] = *reinterpret_cast<const bf16x8*>(
                        W1p + ((size_t)(n16 * 16 + ksg) * 64 + l) * 8);
                }
                bf16x8 a[8];
#pragma unroll
                for (int mf = 0; mf < 8; ++mf) {
                    int row = mf * 16 + lr;
                    int kc = it * 8 + ks * 4 + lg;
                    int slot = (kc + ((row & 7) << 2)) & 31;
                    a[mf] = *reinterpret_cast<const bf16x8*>(
                        sAb + (size_t)(row * 32 + slot) * 16);
                }
#pragma unroll
                for (int nf = 0; nf < 4; ++nf)
#pragma unroll
                    for (int mf = 0; mf < 8; ++mf)
                        acc[mf][nf] = __builtin_amdgcn_mfma_f32_16x16x32_bf16(
                            a[mf], b[nf], acc[mf][nf], 0, 0, 0);
            }
        }
    }

    __syncthreads();  // sA dead; alias as per-wave transpose scratch

    const float* bp = (ct == 0) ? b0 : (ct == 1) ? b1 : (ct == 2) ? b2 : b3;
    ushort* myT = smem + (size_t)w * 2560;  // [128][20] per wave

#pragma unroll
    for (int nf = 0; nf < 4; ++nf) {
        float bv = bp[w * 64 + nf * 16 + lr];
#pragma unroll
        for (int mf = 0; mf < 8; ++mf)
#pragma unroll
            for (int r = 0; r < 4; ++r) {
                float v = acc[mf][nf][r] + bv;
                v = v > 0.f ? v : 0.f;
                myT[(mf * 16 + lg * 4 + r) * 20 + lr] = f2bf(v);
            }
#pragma unroll
        for (int rr = 0; rr < 4; ++rr) {
            int idx = rr * 64 + l;
            int row = idx >> 1, half = idx & 1;
            ushort8 o = *reinterpret_cast<const ushort8*>(myT + row * 20 + half * 8);
            *reinterpret_cast<ushort8*>(
                hid + (size_t)(mt * 128 + row) * 1024 +
                ct * 256 + w * 64 + nf * 16 + half * 8) = o;
        }
    }
}

// ---------------------------------------------------------------------------
// Layer-2 (4 block GEMMs via MFMA) + mixer, fused. 32 samples / wg. (unchanged)
// ---------------------------------------------------------------------------
__global__ __launch_bounds__(256) void k_l2mix(
    const ushort* __restrict__ hid, const ushort* __restrict__ W2p,
    const float* __restrict__ bw1, const float* __restrict__ bb1,
    const float* __restrict__ bw2, const float* __restrict__ bb2,
    const float* __restrict__ q, float* __restrict__ out, int m0)
{
    __shared__ float sO[32 * 336];  // 43 KB
    int tid = threadIdx.x, l = tid & 63, w = tid >> 6;
    int lr = l & 15, lg = l >> 4;
    int sb = blockIdx.x * 32;

    const int fs[5] = {0, 6, 12, 17, 21};
    int jloaded = -1;
    bf16x8 a[2][8];
    for (int f = fs[w]; f < fs[w + 1]; ++f) {
        int j = (f < 12) ? 0 : (f < 16) ? 1 : (f < 20) ? 2 : 3;
        if (j != jloaded) {
#pragma unroll
            for (int mf = 0; mf < 2; ++mf)
#pragma unroll
                for (int ks = 0; ks < 8; ++ks)
                    a[mf][ks] = *reinterpret_cast<const bf16x8*>(
                        hid + (size_t)(sb + mf * 16 + lr) * 1024 + j * 256 + ks * 32 + lg * 8);
            jloaded = j;
        }
        f32x4 acc[2] = {};
#pragma unroll
        for (int ks = 0; ks < 8; ++ks) {
            bf16x8 b = *reinterpret_cast<const bf16x8*>(W2p + ((size_t)(f * 8 + ks) * 64 + l) * 8);
            acc[0] = __builtin_amdgcn_mfma_f32_16x16x32_bf16(a[0][ks], b, acc[0], 0, 0, 0);
            acc[1] = __builtin_amdgcn_mfma_f32_16x16x32_bf16(a[1][ks], b, acc[1], 0, 0, 0);
        }
        int colg = f * 16 + lr;
        float bv = 0.f; bool doabs = false;
        if (colg < 192)       { bv = bw1[colg];       doabs = true; }
        else if (colg < 256)  { bv = bb1[colg - 192]; doabs = false; }
        else if (colg < 320)  { bv = bw2[colg - 256]; doabs = true; }
        else if (colg == 320) { bv = bb2[0];          doabs = false; }
#pragma unroll
        for (int mf = 0; mf < 2; ++mf)
#pragma unroll
            for (int r = 0; r < 4; ++r) {
                float v = acc[mf][r] + bv;
                if (doabs) v = fabsf(v);
                sO[(mf * 16 + lg * 4 + r) * 336 + colg] = v;
            }
    }
    __syncthreads();

    // mixer: 8 threads per sample, each covers 8 of the 64 hidden units
    int sm = tid >> 3, oct = tid & 7;
    const float* qs = q + (size_t)(m0 + sb + sm) * 3;
    float q0 = qs[0], q1 = qs[1], q2 = qs[2];
    const float* ob = sO + sm * 336;
    float res[3];
#pragma unroll
    for (int n = 0; n < 3; ++n) {
        float qa, qb, qc;
        if (n == 0)      { qa = q0; qb = q1; qc = q2; }
        else if (n == 1) { qa = q1; qb = q0; qc = q2; }
        else             { qa = q2; qb = q0; qc = q1; }
        float accm = 0.f;
#pragma unroll
        for (int hh = 0; hh < 8; ++hh) {
            int hc = oct * 8 + hh;
            float hv = ob[192 + hc] + qa * ob[hc] + qb * ob[64 + hc] + qc * ob[128 + hc];
            float ev = hv > 0.f ? hv : expm1f(hv);
            accm += ev * ob[256 + hc];
        }
        accm += __shfl_xor(accm, 1);
        accm += __shfl_xor(accm, 2);
        accm += __shfl_xor(accm, 4);
        res[n] = accm;
    }
    if (oct == 0) {
        float b2v = ob[320];
        float* op = out + (size_t)(m0 + sb + sm) * 3;
        op[0] = res[0] + b2v;
        op[1] = res[1] + b2v;
        op[2] = res[2] + b2v;
    }
}

extern "C" void kernel_launch(void* const* d_in, const int* in_sizes, int n_in,
                              void* d_out, int out_size, void* d_ws, size_t ws_size,
                              hipStream_t stream)
{
    const float* q      = (const float*)d_in[0];
    const float* S      = (const float*)d_in[1];
    const float* hw1_W1 = (const float*)d_in[2];
    const float* hw1_b1 = (const float*)d_in[3];
    const float* hw1_W2 = (const float*)d_in[4];
    const float* hw1_b2 = (const float*)d_in[5];
    const float* hb1_W1 = (const float*)d_in[6];
    const float* hb1_b1 = (const float*)d_in[7];
    const float* hb1_W2 = (const float*)d_in[8];
    const float* hb1_b2 = (const float*)d_in[9];
    const float* hw2_W1 = (const float*)d_in[10];
    const float* hw2_b1 = (const float*)d_in[11];
    const float* hw2_W2 = (const float*)d_in[12];
    const float* hw2_b2 = (const float*)d_in[13];
    const float* hb2_W1 = (const float*)d_in[14];
    const float* hb2_b1 = (const float*)d_in[15];
    const float* hb2_W2 = (const float*)d_in[16];
    const float* hb2_b2 = (const float*)d_in[17];

    int TB = in_sizes[1] / 512;

    ushort* W1p = (ushort*)d_ws;            // 1 MB (65536 chunks * 16 B)
    ushort* W2p = W1p + (size_t)65536 * 8;  // 168 KB
    ushort* hid = W2p + (size_t)10752 * 8;
    size_t used = (size_t)(65536 + 10752) * 16;
    size_t hid_cap = (ws_size > used) ? (ws_size - used) : 0;
    long long max_chunk = (long long)(hid_cap / 2048);  // samples (1024 bf16 each)
    max_chunk &= ~127LL;
    if (max_chunk > TB) max_chunk = TB;
    if (max_chunk < 128) max_chunk = 128;  // best effort

    k_pack<<<dim3(298), dim3(256), 0, stream>>>(
        hw1_W1, hb1_W1, hw2_W1, hb2_W1,
        hw1_W2, hb1_W2, hw2_W2, hb2_W2, W1p, W2p);

    for (int m0 = 0; m0 < TB; m0 += (int)max_chunk) {
        int mc = TB - m0;
        if (mc > max_chunk) mc = (int)max_chunk;
        k_l1<<<dim3(mc / 128, 4), dim3(256), 0, stream>>>(
            S, W1p, hw1_b1, hb1_b1, hw2_b1, hb2_b1, hid, m0);
        k_l2mix<<<dim3(mc / 32), dim3(256), 0, stream>>>(
            hid, W2p, hw1_b2, hb1_b2, hw2_b2, hb2_b2, q, (float*)d_out, m0);
    }
}